// Round 11
// baseline (116.524 us; speedup 1.0000x reference)
//
#include <hip/hip_runtime.h>
#include <math.h>

// Fused Actor network via single-term fp16 MFMA. Round 11: fit 128 total regs/wave.
// r10 evidence: waves_per_eu(2) -> VGPR 120 arch + 64 AGPR acc = ~184 > 128 -> 2 waves/SIMD
// (1 block/CU, occupancy 22%). Fix: cap live accs at 32 (E1 split into two 16-col passes,
// pass-0 results staged in the dead G buffer instead of hold regs) and trim arch pressure.
// A3 softmax parallelized across all 512 threads (shfl reduce) instead of 64-thread serial.
// Block = 64 samples, 512 threads = 8 waves, LDS 66,048 B -> 2 blocks/CU (LDS-wise).
// Weights pre-tiled in d_ws as B-fragment tiles (per-wave 1KB coalesced bursts).
// LDS XOR-swizzle: byte ^= (row&7)<<4.

typedef __attribute__((ext_vector_type(8))) _Float16 half8;
typedef __attribute__((ext_vector_type(4))) _Float16 half4;
typedef __attribute__((ext_vector_type(4))) float    f32x4;

#define MFMA16(a, b, c) __builtin_amdgcn_mfma_f32_16x16x32_f16((a), (b), (c), 0, 0, 0)
#define SWZ(row) (((row) & 7) << 4)

#define MT 64
#define T  512

// ---- LDS byte offsets (total 66,048 B) ----
// S  [0, 49152): 64 rows x 384 f16 (stride 768B); cols 376..383 zero-padded.
// G  [49152, 65536): 64x128 f16 (stride 256B). Holds G1, then G2, then E1-pass0 temp.
// CF [65536, 66048): 64 x (c0h,c0l,c1h,c1l) fp16 = 8B/row.
// H1 [0, 32768): 64x256 f16 (stride 512B), overlays S (dead after E1 accumulation).
// H2 [32768, 49152): 64x128 f16 (stride 256B), overlays rest of S.
#define S_B      0
#define G_B      49152
#define CF_B     65536
#define H1_B     0
#define H2_B     32768
#define LDS_BYTES 66048

// ---- ws half-element offsets; tiled: tile(n0,kc) at ((n0*KC+kc)*512), inner [lane][8] ----
#define WS_W1 0        /* bw1: N0=8,  KC=12 -> 49152 halfs */
#define WS_W2 49152    /* bw2: N0=8,  KC=4  -> 16384 */
#define WS_E1 65536    /* ew1: N0=32, KC=12 -> 196608 */
#define WS_E2 262144   /* ew2: N0=16, KC=8  -> 65536 */
#define WS_EM 327680   /* ewm: N0=4,  KC=4  -> 8192 (2 experts x 32 rows padded) */
#define WS_HALFS 335872
#define WS_BYTES 671744

__device__ __forceinline__ half8 cvt8(const float* __restrict__ p) {
    const float4 a = *reinterpret_cast<const float4*>(p);
    const float4 b = *reinterpret_cast<const float4*>(p + 4);
    half8 r;
    r[0] = (_Float16)a.x; r[1] = (_Float16)a.y; r[2] = (_Float16)a.z; r[3] = (_Float16)a.w;
    r[4] = (_Float16)b.x; r[5] = (_Float16)b.y; r[6] = (_Float16)b.z; r[7] = (_Float16)b.w;
    return r;
}

// ================= prep kernel: fp32 weights -> fp16 B-fragment tiles in ws =================
// For W[N][K]: tile t = n0*KC + kc; half index = l*8 + j -> n = n0*16 + (l&15),
// k = kc*32 + (l>>4)*8 + j. Out-of-range (n,k) -> 0.
__global__ __launch_bounds__(256)
void prep_weights(const float* __restrict__ bw1, const float* __restrict__ bw2,
                  const float* __restrict__ ew1, const float* __restrict__ ew2,
                  const float* __restrict__ ewm, _Float16* __restrict__ wsw)
{
    const int i = blockIdx.x * 256 + threadIdx.x;
    if (i >= WS_HALFS) return;
    const float* W; int N, K, KC, j0;
    if      (i < 49152)  { W = bw1; N = 128; K = 376; KC = 12; j0 = i - WS_W1; }
    else if (i < 65536)  { W = bw2; N = 128; K = 128; KC = 4;  j0 = i - WS_W2; }
    else if (i < 262144) { W = ew1; N = 512; K = 376; KC = 12; j0 = i - WS_E1; }
    else if (i < 327680) { W = ew2; N = 256; K = 256; KC = 8;  j0 = i - WS_E2; }
    else                 { W = ewm; N = 34;  K = 128; KC = 4;  j0 = i - WS_EM; }
    const int tile = j0 >> 9;
    const int rem  = j0 & 511;
    const int l    = rem >> 3;
    const int jj   = rem & 7;
    const int n0   = tile / KC, kc = tile - n0 * KC;
    int n = n0 * 16 + (l & 15);
    const int k = kc * 32 + (l >> 4) * 8 + jj;
    float v = 0.f;
    if (W == ewm) {  // ewm logical rows: 2 experts x 32 padded rows -> src 2 x 17
        const int e = n >> 5, a = n & 31;
        if (a < 17 && k < K) v = ewm[(e * 17 + a) * K + k];
    } else {
        if (n < N && k < K) v = W[n * K + k];
    }
    wsw[i] = (_Float16)v;
}

// ================= fused actor kernel =================
template <bool USE_WS>
__global__ __launch_bounds__(512)
__attribute__((amdgpu_waves_per_eu(2)))
void actor_kernel(const float* __restrict__ states,
                  const float* __restrict__ bw1, const float* __restrict__ bb1,
                  const float* __restrict__ bw2, const float* __restrict__ bb2,
                  const float* __restrict__ bwo, const float* __restrict__ bbo,
                  const float* __restrict__ ew1, const float* __restrict__ eb1,
                  const float* __restrict__ ew2, const float* __restrict__ eb2,
                  const float* __restrict__ ewm, const float* __restrict__ ebm,
                  const _Float16* __restrict__ wsw,
                  float* __restrict__ out)
{
    extern __shared__ char smc[];
    const int t    = threadIdx.x;
    const int l    = t & 63;
    const int l15  = l & 15;
    const int kgrp = l >> 4;          // 0..3
    const int kg16 = kgrp * 16;       // byte offset within a 32-col (64B) chunk
    const int wv   = __builtin_amdgcn_readfirstlane(t >> 6);
    const int base = blockIdx.x * MT;
    const int lB   = l * 8;           // half offset of this lane's frag within a ws tile

    const half8 zf = {0,0,0,0,0,0,0,0};

    // ---------- stage: states fp32 -> fp16 in LDS (swizzled) ----------
    {
        const float4* src = reinterpret_cast<const float4*>(states + (long)base * 376);
        for (int q = t; q < MT * 94; q += T) {
            const int r  = q / 94;
            const int c4 = q - r * 94;
            const float4 v = src[q];
            half4 h;
            h[0] = (_Float16)v.x; h[1] = (_Float16)v.y;
            h[2] = (_Float16)v.z; h[3] = (_Float16)v.w;
            *(half4*)(smc + S_B + ((r * 768 + c4 * 8) ^ SWZ(r))) = h;
        }
        if (t < MT) {  // zero K-pad cols 376..383 (bytes 752..768)
            *(float4*)(smc + S_B + ((t * 768 + 752) ^ SWZ(t))) = make_float4(0.f, 0.f, 0.f, 0.f);
        }
    }
    __syncthreads();

    // ---------- A1: G1 = relu(S @ bw1^T + bb1)  M=64 N=128 K=384 ----------
    {
        f32x4 acc[4] = {{0,0,0,0},{0,0,0,0},{0,0,0,0},{0,0,0,0}};
        const int col = wv * 16 + l15;
        for (int kc = 0; kc < 12; ++kc) {
            half8 bf;
            if constexpr (USE_WS) bf = *(const half8*)(wsw + WS_W1 + (wv * 12 + kc) * 512 + lB);
            else {
                const int g = kc * 4 + kgrp;
                bf = (g < 47) ? cvt8(bw1 + col * 376 + g * 8) : zf;
            }
            const int koff = kc * 64 + kg16;
            #pragma unroll
            for (int mt = 0; mt < 4; ++mt) {
                const int row = mt * 16 + l15;
                const half8 af = *(const half8*)(smc + S_B + ((row * 768 + koff) ^ SWZ(row)));
                acc[mt] = MFMA16(af, bf, acc[mt]);
            }
        }
        const float bias = bb1[col];
        #pragma unroll
        for (int mt = 0; mt < 4; ++mt) {
            #pragma unroll
            for (int j = 0; j < 4; ++j) {
                const int row = mt * 16 + kgrp * 4 + j;
                const float v = fmaxf(acc[mt][j] + bias, 0.f);
                *(_Float16*)(smc + G_B + ((row * 256 + col * 2) ^ SWZ(row))) = (_Float16)v;
            }
        }
    }
    __syncthreads();

    // ---------- A2: G2 = relu(G1 @ bw2^T + bb2)  M=64 N=128 K=128 (G reused) ----------
    {
        f32x4 acc[4] = {{0,0,0,0},{0,0,0,0},{0,0,0,0},{0,0,0,0}};
        const int col = wv * 16 + l15;
        for (int kc = 0; kc < 4; ++kc) {
            half8 bf;
            if constexpr (USE_WS) bf = *(const half8*)(wsw + WS_W2 + (wv * 4 + kc) * 512 + lB);
            else                  bf = cvt8(bw2 + col * 128 + (kc * 4 + kgrp) * 8);
            const int koff = kc * 64 + kg16;
            #pragma unroll
            for (int mt = 0; mt < 4; ++mt) {
                const int row = mt * 16 + l15;
                const half8 af = *(const half8*)(smc + G_B + ((row * 256 + koff) ^ SWZ(row)));
                acc[mt] = MFMA16(af, bf, acc[mt]);
            }
        }
        __syncthreads();   // all G1 reads complete before overwrite
        const float bias = bb2[col];
        #pragma unroll
        for (int mt = 0; mt < 4; ++mt) {
            #pragma unroll
            for (int j = 0; j < 4; ++j) {
                const int row = mt * 16 + kgrp * 4 + j;
                const float v = fmaxf(acc[mt][j] + bias, 0.f);
                *(_Float16*)(smc + G_B + ((row * 256 + col * 2) ^ SWZ(row))) = (_Float16)v;
            }
        }
    }
    __syncthreads();

    // ---------- A3: softmax coeffs, all 512 threads ----------
    // thread -> (sample s = t>>3, expert e = t&1, k-chunk = (t>>1)&3); shfl-reduce chunks.
    {
        const int s     = t >> 3;
        const int r     = t & 7;
        const int e     = r & 1;
        const int chunk = r >> 1;
        float z = 0.f;
        const float* wo = bwo + e * 128 + chunk * 32;
        #pragma unroll
        for (int q = 0; q < 4; ++q) {
            const half8 hv = *(const half8*)(smc + G_B + ((s * 256 + chunk * 64 + q * 16) ^ SWZ(s)));
            const float4 w0 = *(const float4*)(wo + q * 8);
            const float4 w1 = *(const float4*)(wo + q * 8 + 4);
            z = fmaf((float)hv[0], w0.x, z); z = fmaf((float)hv[1], w0.y, z);
            z = fmaf((float)hv[2], w0.z, z); z = fmaf((float)hv[3], w0.w, z);
            z = fmaf((float)hv[4], w1.x, z); z = fmaf((float)hv[5], w1.y, z);
            z = fmaf((float)hv[6], w1.z, z); z = fmaf((float)hv[7], w1.w, z);
        }
        z += __shfl_xor(z, 2, 64);     // sum chunk bit 0
        z += __shfl_xor(z, 4, 64);     // sum chunk bit 1
        z += bbo[e];
        const float zo = __shfl_xor(z, 1, 64);   // other expert's logit
        if (r < 2) {
            const float m = fmaxf(z, zo);
            const float ea = __expf(z - m), eb = __expf(zo - m);
            const float c_self = ea / (ea + eb);
            const _Float16 ch = (_Float16)c_self;
            const _Float16 cl = (_Float16)(c_self - (float)ch);
            union { _Float16 h[2]; unsigned u; } pk;
            pk.h[0] = ch; pk.h[1] = cl;
            *(unsigned*)(smc + CF_B + s * 8 + e * 4) = pk.u;
        }
    }
    __syncthreads();

    // ---------- E1: H1 = relu(blend(S @ ew1[e]^T + eb1[e]))  M=64 N=256x2 K=384 ----------
    // Two sequential 16-col passes, 32 accs live each. Pass-0 results -> G (dead) as temp;
    // pass-1 accs survive the S-death barrier in regs; then both written to H1.
    {
        f32x4 aA[4], aB[4];
        // ---- pass 0: cols wv*32 + 0..15 ----
        #pragma unroll
        for (int mt = 0; mt < 4; ++mt) { aA[mt] = {0,0,0,0}; aB[mt] = {0,0,0,0}; }
        for (int kc = 0; kc < 12; ++kc) {
            half8 b0, b1;
            if constexpr (USE_WS) {
                const int n0 = wv * 2;
                b0 = *(const half8*)(wsw + WS_E1 + (n0 * 12 + kc) * 512 + lB);
                b1 = *(const half8*)(wsw + WS_E1 + ((16 + n0) * 12 + kc) * 512 + lB);
            } else {
                const int g = kc * 4 + kgrp;
                const int wr = wv * 32 + l15;
                b0 = (g < 47) ? cvt8(ew1 + wr * 376 + g * 8)         : zf;
                b1 = (g < 47) ? cvt8(ew1 + (wr + 256) * 376 + g * 8) : zf;
            }
            const int koff = kc * 64 + kg16;
            #pragma unroll
            for (int mt = 0; mt < 4; ++mt) {
                const int row = mt * 16 + l15;
                const half8 af = *(const half8*)(smc + S_B + ((row * 768 + koff) ^ SWZ(row)));
                aA[mt] = MFMA16(af, b0, aA[mt]);
                aB[mt] = MFMA16(af, b1, aB[mt]);
            }
        }
        {   // pass-0 epilogue -> G temp (gcol = wv*16+l15 slot in G's 128 cols)
            const int col  = wv * 32 + l15;
            const int gcol = wv * 16 + l15;
            const float be0 = eb1[col], be1 = eb1[256 + col];
            #pragma unroll
            for (int mt = 0; mt < 4; ++mt) {
                #pragma unroll
                for (int j = 0; j < 4; ++j) {
                    const int row = mt * 16 + kgrp * 4 + j;
                    const half4 cc = *(const half4*)(smc + CF_B + row * 8);
                    const float c0 = (float)cc[0] + (float)cc[1];
                    const float c1 = (float)cc[2] + (float)cc[3];
                    const float v = c0 * (aA[mt][j] + be0) + c1 * (aB[mt][j] + be1);
                    *(_Float16*)(smc + G_B + ((row * 256 + gcol * 2) ^ SWZ(row))) = (_Float16)fmaxf(v, 0.f);
                }
            }
        }
        // ---- pass 1: cols wv*32 + 16..31 ----
        #pragma unroll
        for (int mt = 0; mt < 4; ++mt) { aA[mt] = {0,0,0,0}; aB[mt] = {0,0,0,0}; }
        for (int kc = 0; kc < 12; ++kc) {
            half8 b0, b1;
            if constexpr (USE_WS) {
                const int n0 = wv * 2 + 1;
                b0 = *(const half8*)(wsw + WS_E1 + (n0 * 12 + kc) * 512 + lB);
                b1 = *(const half8*)(wsw + WS_E1 + ((16 + n0) * 12 + kc) * 512 + lB);
            } else {
                const int g = kc * 4 + kgrp;
                const int wr = wv * 32 + 16 + l15;
                b0 = (g < 47) ? cvt8(ew1 + wr * 376 + g * 8)         : zf;
                b1 = (g < 47) ? cvt8(ew1 + (wr + 256) * 376 + g * 8) : zf;
            }
            const int koff = kc * 64 + kg16;
            #pragma unroll
            for (int mt = 0; mt < 4; ++mt) {
                const int row = mt * 16 + l15;
                const half8 af = *(const half8*)(smc + S_B + ((row * 768 + koff) ^ SWZ(row)));
                aA[mt] = MFMA16(af, b0, aA[mt]);
                aB[mt] = MFMA16(af, b1, aB[mt]);
            }
        }
        __syncthreads();   // ALL waves' S reads complete; H1 may overlay S
        {   // pass-1 epilogue -> H1 directly
            const int col = wv * 32 + 16 + l15;
            const float be0 = eb1[col], be1 = eb1[256 + col];
            #pragma unroll
            for (int mt = 0; mt < 4; ++mt) {
                #pragma unroll
                for (int j = 0; j < 4; ++j) {
                    const int row = mt * 16 + kgrp * 4 + j;
                    const half4 cc = *(const half4*)(smc + CF_B + row * 8);
                    const float c0 = (float)cc[0] + (float)cc[1];
                    const float c1 = (float)cc[2] + (float)cc[3];
                    const float v = c0 * (aA[mt][j] + be0) + c1 * (aB[mt][j] + be1);
                    *(_Float16*)(smc + H1_B + ((row * 512 + col * 2) ^ SWZ(row))) = (_Float16)fmaxf(v, 0.f);
                }
            }
        }
        {   // copy pass-0 temp (this thread's own writes) G -> H1
            const int col  = wv * 32 + l15;
            const int gcol = wv * 16 + l15;
            #pragma unroll
            for (int mt = 0; mt < 4; ++mt) {
                #pragma unroll
                for (int j = 0; j < 4; ++j) {
                    const int row = mt * 16 + kgrp * 4 + j;
                    const _Float16 hv = *(const _Float16*)(smc + G_B + ((row * 256 + gcol * 2) ^ SWZ(row)));
                    *(_Float16*)(smc + H1_B + ((row * 512 + col * 2) ^ SWZ(row))) = hv;
                }
            }
        }
    }
    __syncthreads();

    // ---------- E2: H2 = relu(blend(H1 @ ew2[e]^T + eb2[e]))  M=64 N=128x2 K=256 ----------
    {
        f32x4 cA[4], cB[4];
        #pragma unroll
        for (int mt = 0; mt < 4; ++mt) { cA[mt] = {0,0,0,0}; cB[mt] = {0,0,0,0}; }
        const int col = wv * 16 + l15;
        for (int kc = 0; kc < 8; ++kc) {
            half8 b0, b1;
            if constexpr (USE_WS) {
                b0 = *(const half8*)(wsw + WS_E2 + (wv * 8 + kc) * 512 + lB);
                b1 = *(const half8*)(wsw + WS_E2 + ((8 + wv) * 8 + kc) * 512 + lB);
            } else {
                const int g = kc * 4 + kgrp;
                b0 = cvt8(ew2 + col * 256 + g * 8);
                b1 = cvt8(ew2 + (col + 128) * 256 + g * 8);
            }
            const int koff = kc * 64 + kg16;
            #pragma unroll
            for (int mt = 0; mt < 4; ++mt) {
                const int row = mt * 16 + l15;
                const half8 af = *(const half8*)(smc + H1_B + ((row * 512 + koff) ^ SWZ(row)));
                cA[mt] = MFMA16(af, b0, cA[mt]);
                cB[mt] = MFMA16(af, b1, cB[mt]);
            }
        }
        __syncthreads();   // all H1 reads done before H2 write
        const float b0 = eb2[col], b1 = eb2[128 + col];
        #pragma unroll
        for (int mt = 0; mt < 4; ++mt) {
            #pragma unroll
            for (int j = 0; j < 4; ++j) {
                const int row = mt * 16 + kgrp * 4 + j;
                const half4 cc = *(const half4*)(smc + CF_B + row * 8);
                const float c0 = (float)cc[0] + (float)cc[1];
                const float c1 = (float)cc[2] + (float)cc[3];
                float v = c0 * (cA[mt][j] + b0) + c1 * (cB[mt][j] + b1);
                v = fmaxf(v, 0.f);
                *(_Float16*)(smc + H2_B + ((row * 256 + col * 2) ^ SWZ(row))) = (_Float16)v;
            }
        }
    }
    __syncthreads();

    // ---------- E3: mu = tanh(blend(H2 @ ewm[e]^T + ebm[e]))  M=64 N=17x2 K=128 ----------
    {
        const int colt = wv & 1;      // col tile (2x16 covers 17)
        const int mt   = wv >> 1;     // row tile 0..3
        f32x4 c0a = {0,0,0,0}, c1a = {0,0,0,0};
        const int col  = colt * 16 + l15;
        const bool vcol = (col < 17);
        const int arow = mt * 16 + l15;
        for (int kc = 0; kc < 4; ++kc) {
            const int koff = kc * 64 + kg16;
            const half8 af = *(const half8*)(smc + H2_B + ((arow * 256 + koff) ^ SWZ(arow)));
            half8 b0, b1;
            if constexpr (USE_WS) {
                b0 = *(const half8*)(wsw + WS_EM + (colt * 4 + kc) * 512 + lB);
                b1 = *(const half8*)(wsw + WS_EM + ((2 + colt) * 4 + kc) * 512 + lB);
            } else {
                const int g = kc * 4 + kgrp;
                b0 = vcol ? cvt8(ewm + col * 128 + g * 8)        : zf;
                b1 = vcol ? cvt8(ewm + (17 + col) * 128 + g * 8) : zf;
            }
            c0a = MFMA16(af, b0, c0a);
            c1a = MFMA16(af, b1, c1a);
        }
        if (vcol) {
            const float b0 = ebm[col], b1 = ebm[17 + col];
            #pragma unroll
            for (int j = 0; j < 4; ++j) {
                const int row = mt * 16 + kgrp * 4 + j;
                const half4 cc = *(const half4*)(smc + CF_B + row * 8);
                const float c0 = (float)cc[0] + (float)cc[1];
                const float c1 = (float)cc[2] + (float)cc[3];
                const float v = c0 * (c0a[j] + b0) + c1 * (c1a[j] + b1);
                out[(long)(base + row) * 17 + col] = tanhf(v);
            }
        }
    }
}

extern "C" void kernel_launch(void* const* d_in, const int* in_sizes, int n_in,
                              void* d_out, int out_size, void* d_ws, size_t ws_size,
                              hipStream_t stream) {
    (void)in_sizes; (void)n_in; (void)out_size;
    const float* states = (const float*)d_in[0];
    const float* bw1 = (const float*)d_in[1];
    const float* bb1 = (const float*)d_in[2];
    const float* bw2 = (const float*)d_in[3];
    const float* bb2 = (const float*)d_in[4];
    const float* bwo = (const float*)d_in[5];
    const float* bbo = (const float*)d_in[6];
    const float* ew1 = (const float*)d_in[7];
    const float* eb1 = (const float*)d_in[8];
    const float* ew2 = (const float*)d_in[9];
    const float* eb2 = (const float*)d_in[10];
    const float* ewm = (const float*)d_in[11];
    const float* ebm = (const float*)d_in[12];
    float* out = (float*)d_out;

    const int nblk = 65536 / MT;   // 1024

    if (d_ws != nullptr && ws_size >= (size_t)WS_BYTES) {
        _Float16* wsw = (_Float16*)d_ws;
        prep_weights<<<dim3((WS_HALFS + 255) / 256), dim3(256), 0, stream>>>(
            bw1, bw2, ew1, ew2, ewm, wsw);
        actor_kernel<true><<<dim3(nblk), dim3(T), LDS_BYTES, stream>>>(
            states, bw1, bb1, bw2, bb2, bwo, bbo,
            ew1, eb1, ew2, eb2, ewm, ebm, wsw, out);
    } else {
        actor_kernel<false><<<dim3(nblk), dim3(T), LDS_BYTES, stream>>>(
            states, bw1, bb1, bw2, bb2, bwo, bbo,
            ew1, eb1, ew2, eb2, ewm, ebm, nullptr, out);
    }
}

// Round 12
// 86.822 us; speedup vs baseline: 1.3421x; 1.3421x over previous
//
#include <hip/hip_runtime.h>
#include <math.h>

// Fused Actor network via single-term fp16 MFMA. Round 12: r6 base + weight prefetch.
// r6 (96us) re-baseline with: (1) depth-1 manual prefetch of weight B-frags in all
// K-loops (expose-L2-latency theory: rolled loops serialized ~300cy L2 loads per kc),
// (2) A3 softmax parallelized across all 512 threads (shfl reduce),
// (3) waves_per_eu(2): (4)/(4,4) provably squeeze to 64 regs + spill; (2) allocates
//     ~demand (r10: 120 regs, no spill). LDS still caps occupancy at 2 blocks/CU.
// Block = 32 samples, 512 threads = 8 waves, LDS 40,960 B -> 2 blocks/CU.
// Weights pre-tiled in d_ws as B-fragment tiles (per-wave 1KB coalesced bursts).
// LDS XOR-swizzle: byte ^= (row&7)<<4.

typedef __attribute__((ext_vector_type(8))) _Float16 half8;
typedef __attribute__((ext_vector_type(4))) _Float16 half4;
typedef __attribute__((ext_vector_type(4))) float    f32x4;

#define MFMA16(a, b, c) __builtin_amdgcn_mfma_f32_16x16x32_f16((a), (b), (c), 0, 0, 0)
#define SWZ(row) (((row) & 7) << 4)

#define MT 32
#define T  512

// ---- LDS byte offsets (total 40,960 B) ----
// S  [0, 24576): 32 rows x 384 f16 (stride 768B); cols 376..383 zero-padded;
//    after A3 pad bytes 752..759 hold (c0h,c0l,c1h,c1l) fp16 per row.
// G1 [24576, 32768): 32x128 f16 (stride 256B)
// G2 [32768, 40960): 32x128 f16
// H1 [24576, 40960): 32x256 f16 (stride 512B), overlays G1+G2
// H2 [24576, 32768): 32x128 f16, overlays H1 low half (barrier between read + write)
#define S_B      0
#define G1_B     24576
#define G2_B     32768
#define H1_B     24576
#define H2_B     24576
#define LDS_BYTES 40960

// ---- ws half-element offsets; tiled layout: tile(n0,kc) at ((n0*KC+kc)*512), [lane][8] ----
#define WS_W1 0        /* bw1: N0=8,  KC=12 -> 49152 halfs */
#define WS_W2 49152    /* bw2: N0=8,  KC=4  -> 16384 */
#define WS_E1 65536    /* ew1: N0=32, KC=12 -> 196608 */
#define WS_E2 262144   /* ew2: N0=16, KC=8  -> 65536 */
#define WS_EM 327680   /* ewm: N0=4,  KC=4  -> 8192 (2 experts x 32 rows padded) */
#define WS_HALFS 335872
#define WS_BYTES 671744

__device__ __forceinline__ half8 cvt8(const float* __restrict__ p) {
    const float4 a = *reinterpret_cast<const float4*>(p);
    const float4 b = *reinterpret_cast<const float4*>(p + 4);
    half8 r;
    r[0] = (_Float16)a.x; r[1] = (_Float16)a.y; r[2] = (_Float16)a.z; r[3] = (_Float16)a.w;
    r[4] = (_Float16)b.x; r[5] = (_Float16)b.y; r[6] = (_Float16)b.z; r[7] = (_Float16)b.w;
    return r;
}

// ================= prep kernel: fp32 weights -> fp16 B-fragment tiles in ws =================
// For a matrix W[N][K]: tile t = n0*KC + kc; within tile, half index = l*8 + j maps to
// n = n0*16 + (l&15), k = kc*32 + (l>>4)*8 + j. Out-of-range (n,k) -> 0.
__global__ __launch_bounds__(256)
void prep_weights(const float* __restrict__ bw1, const float* __restrict__ bw2,
                  const float* __restrict__ ew1, const float* __restrict__ ew2,
                  const float* __restrict__ ewm, _Float16* __restrict__ wsw)
{
    const int i = blockIdx.x * 256 + threadIdx.x;
    if (i >= WS_HALFS) return;
    const float* W; int N, K, KC, j0;
    if      (i < 49152)  { W = bw1; N = 128; K = 376; KC = 12; j0 = i - WS_W1; }
    else if (i < 65536)  { W = bw2; N = 128; K = 128; KC = 4;  j0 = i - WS_W2; }
    else if (i < 262144) { W = ew1; N = 512; K = 376; KC = 12; j0 = i - WS_E1; }
    else if (i < 327680) { W = ew2; N = 256; K = 256; KC = 8;  j0 = i - WS_E2; }
    else                 { W = ewm; N = 34;  K = 128; KC = 4;  j0 = i - WS_EM; }
    const int tile = j0 >> 9;
    const int rem  = j0 & 511;
    const int l    = rem >> 3;
    const int jj   = rem & 7;
    const int n0   = tile / KC, kc = tile - n0 * KC;
    int n = n0 * 16 + (l & 15);
    const int k = kc * 32 + (l >> 4) * 8 + jj;
    float v = 0.f;
    if (W == ewm) {  // ewm logical rows: 2 experts x 32 padded rows -> src 2 x 17
        const int e = n >> 5, a = n & 31;
        if (a < 17 && k < K) v = ewm[(e * 17 + a) * K + k];
    } else {
        if (n < N && k < K) v = W[n * K + k];
    }
    wsw[i] = (_Float16)v;
}

// ================= fused actor kernel =================
template <bool USE_WS>
__global__ __launch_bounds__(512)
__attribute__((amdgpu_waves_per_eu(2)))
void actor_kernel(const float* __restrict__ states,
                  const float* __restrict__ bw1, const float* __restrict__ bb1,
                  const float* __restrict__ bw2, const float* __restrict__ bb2,
                  const float* __restrict__ bwo, const float* __restrict__ bbo,
                  const float* __restrict__ ew1, const float* __restrict__ eb1,
                  const float* __restrict__ ew2, const float* __restrict__ eb2,
                  const float* __restrict__ ewm, const float* __restrict__ ebm,
                  const _Float16* __restrict__ wsw,
                  float* __restrict__ out)
{
    extern __shared__ char smc[];
    const int t    = threadIdx.x;
    const int l    = t & 63;
    const int l15  = l & 15;
    const int kgrp = l >> 4;          // 0..3
    const int kg16 = kgrp * 16;       // byte offset within a 32-col (64B) chunk
    const int wv   = __builtin_amdgcn_readfirstlane(t >> 6);
    const int base = blockIdx.x * MT;
    const int lB   = l * 8;           // half offset of this lane's frag within a ws tile

    const half8 zf = {0,0,0,0,0,0,0,0};

    // ---------- stage: states fp32 -> fp16 in LDS (swizzled) ----------
    {
        const float4* src = reinterpret_cast<const float4*>(states + (long)base * 376);
        for (int q = t; q < MT * 94; q += T) {
            const int r  = q / 94;
            const int c4 = q - r * 94;
            const float4 v = src[q];
            half4 h;
            h[0] = (_Float16)v.x; h[1] = (_Float16)v.y;
            h[2] = (_Float16)v.z; h[3] = (_Float16)v.w;
            *(half4*)(smc + S_B + ((r * 768 + c4 * 8) ^ SWZ(r))) = h;
        }
        if (t < MT) {  // zero K-pad cols 376..383 (bytes 752..768)
            *(float4*)(smc + S_B + ((t * 768 + 752) ^ SWZ(t))) = make_float4(0.f, 0.f, 0.f, 0.f);
        }
    }
    __syncthreads();

    // ---------- A1: G1 = relu(S @ bw1^T + bb1)  M=32 N=128 K=384 ----------
    {
        f32x4 acc[2] = {{0,0,0,0},{0,0,0,0}};
        const int col = wv * 16 + l15;
        auto ldW = [&](int kc) -> half8 {
            if constexpr (USE_WS) return *(const half8*)(wsw + WS_W1 + (wv * 12 + kc) * 512 + lB);
            else { const int g = kc * 4 + kgrp; return (g < 47) ? cvt8(bw1 + col * 376 + g * 8) : zf; }
        };
        half8 bf = ldW(0);
        #pragma unroll
        for (int kc = 0; kc < 12; ++kc) {
            const half8 cur = bf;
            if (kc < 11) bf = ldW(kc + 1);
            const int koff = kc * 64 + kg16;
            #pragma unroll
            for (int mt = 0; mt < 2; ++mt) {
                const int row = mt * 16 + l15;
                const half8 af = *(const half8*)(smc + S_B + ((row * 768 + koff) ^ SWZ(row)));
                acc[mt] = MFMA16(af, cur, acc[mt]);
            }
        }
        const float bias = bb1[col];
        #pragma unroll
        for (int mt = 0; mt < 2; ++mt) {
            #pragma unroll
            for (int j = 0; j < 4; ++j) {
                const int row = mt * 16 + kgrp * 4 + j;
                const float v = fmaxf(acc[mt][j] + bias, 0.f);
                *(_Float16*)(smc + G1_B + ((row * 256 + col * 2) ^ SWZ(row))) = (_Float16)v;
            }
        }
    }
    __syncthreads();

    // ---------- A2: G2 = relu(G1 @ bw2^T + bb2)  M=32 N=128 K=128 ----------
    {
        f32x4 acc[2] = {{0,0,0,0},{0,0,0,0}};
        const int col = wv * 16 + l15;
        auto ldW = [&](int kc) -> half8 {
            if constexpr (USE_WS) return *(const half8*)(wsw + WS_W2 + (wv * 4 + kc) * 512 + lB);
            else                  return cvt8(bw2 + col * 128 + (kc * 4 + kgrp) * 8);
        };
        half8 bf = ldW(0);
        #pragma unroll
        for (int kc = 0; kc < 4; ++kc) {
            const half8 cur = bf;
            if (kc < 3) bf = ldW(kc + 1);
            const int koff = kc * 64 + kg16;
            #pragma unroll
            for (int mt = 0; mt < 2; ++mt) {
                const int row = mt * 16 + l15;
                const half8 af = *(const half8*)(smc + G1_B + ((row * 256 + koff) ^ SWZ(row)));
                acc[mt] = MFMA16(af, cur, acc[mt]);
            }
        }
        const float bias = bb2[col];
        #pragma unroll
        for (int mt = 0; mt < 2; ++mt) {
            #pragma unroll
            for (int j = 0; j < 4; ++j) {
                const int row = mt * 16 + kgrp * 4 + j;
                const float v = fmaxf(acc[mt][j] + bias, 0.f);
                *(_Float16*)(smc + G2_B + ((row * 256 + col * 2) ^ SWZ(row))) = (_Float16)v;
            }
        }
    }
    __syncthreads();

    // ---------- A3: softmax coeffs, all 512 threads ----------
    // thread -> (sample s = t>>4, r = t&15: expert e = r&1, k-chunk = r>>1 of 16 k each);
    // shfl-xor reduce chunks (masks 2,4,8 stay within the 16-thread sample group).
    {
        const int s     = t >> 4;
        const int r     = t & 15;
        const int e     = r & 1;
        const int chunk = r >> 1;
        float z = 0.f;
        const float* wo = bwo + e * 128 + chunk * 16;
        #pragma unroll
        for (int q = 0; q < 2; ++q) {
            const half8 hv = *(const half8*)(smc + G2_B + ((s * 256 + chunk * 32 + q * 16) ^ SWZ(s)));
            const float4 w0 = *(const float4*)(wo + q * 8);
            const float4 w1 = *(const float4*)(wo + q * 8 + 4);
            z = fmaf((float)hv[0], w0.x, z); z = fmaf((float)hv[1], w0.y, z);
            z = fmaf((float)hv[2], w0.z, z); z = fmaf((float)hv[3], w0.w, z);
            z = fmaf((float)hv[4], w1.x, z); z = fmaf((float)hv[5], w1.y, z);
            z = fmaf((float)hv[6], w1.z, z); z = fmaf((float)hv[7], w1.w, z);
        }
        z += __shfl_xor(z, 2, 64);
        z += __shfl_xor(z, 4, 64);
        z += __shfl_xor(z, 8, 64);
        z += bbo[e];
        const float zo = __shfl_xor(z, 1, 64);   // other expert's logit
        if (r < 2) {
            const float m = fmaxf(z, zo);
            const float ea = __expf(z - m), eb = __expf(zo - m);
            const float c_self = ea / (ea + eb);
            const _Float16 ch = (_Float16)c_self;
            const _Float16 cl = (_Float16)(c_self - (float)ch);
            union { _Float16 h[2]; unsigned u; } pk;
            pk.h[0] = ch; pk.h[1] = cl;
            *(unsigned*)(smc + S_B + (((s * 768 + 752) ^ SWZ(s)) + e * 4)) = pk.u;
        }
    }
    __syncthreads();

    // ---------- E1: H1 = relu(blend(S @ ew1[e]^T + eb1[e]))  M=32 N=256x2 K=384 ----------
    {
        f32x4 aA[2][2], aB[2][2];   // [nt][mt]
        #pragma unroll
        for (int nt = 0; nt < 2; ++nt)
            #pragma unroll
            for (int mt = 0; mt < 2; ++mt) { aA[nt][mt] = {0,0,0,0}; aB[nt][mt] = {0,0,0,0}; }

        auto ldE1 = [&](int kc, int nt, int ex) -> half8 {
            if constexpr (USE_WS) {
                const int n0 = wv * 2 + nt + ex * 16;
                return *(const half8*)(wsw + WS_E1 + (n0 * 12 + kc) * 512 + lB);
            } else {
                const int g = kc * 4 + kgrp;
                const int wr = wv * 32 + nt * 16 + l15 + ex * 256;
                return (g < 47) ? cvt8(ew1 + wr * 376 + g * 8) : zf;
            }
        };
        half8 b00 = ldE1(0, 0, 0), b01 = ldE1(0, 0, 1);
        half8 b10 = ldE1(0, 1, 0), b11 = ldE1(0, 1, 1);
        #pragma unroll
        for (int kc = 0; kc < 12; ++kc) {
            const half8 c00 = b00, c01 = b01, c10 = b10, c11 = b11;
            if (kc < 11) {
                b00 = ldE1(kc + 1, 0, 0); b01 = ldE1(kc + 1, 0, 1);
                b10 = ldE1(kc + 1, 1, 0); b11 = ldE1(kc + 1, 1, 1);
            }
            const int koff = kc * 64 + kg16;
            #pragma unroll
            for (int mt = 0; mt < 2; ++mt) {
                const int row = mt * 16 + l15;
                const half8 af = *(const half8*)(smc + S_B + ((row * 768 + koff) ^ SWZ(row)));
                aA[0][mt] = MFMA16(af, c00, aA[0][mt]);
                aB[0][mt] = MFMA16(af, c01, aB[0][mt]);
                aA[1][mt] = MFMA16(af, c10, aA[1][mt]);
                aB[1][mt] = MFMA16(af, c11, aB[1][mt]);
            }
        }
        #pragma unroll
        for (int nt = 0; nt < 2; ++nt) {
            const int col = wv * 32 + nt * 16 + l15;
            const float b0 = eb1[col], b1 = eb1[256 + col];
            #pragma unroll
            for (int mt = 0; mt < 2; ++mt) {
                #pragma unroll
                for (int j = 0; j < 4; ++j) {
                    const int row = mt * 16 + kgrp * 4 + j;
                    const half4 cc = *(const half4*)(smc + S_B + ((row * 768 + 752) ^ SWZ(row)));
                    const float c0 = (float)cc[0] + (float)cc[1];
                    const float c1 = (float)cc[2] + (float)cc[3];
                    float v = c0 * (aA[nt][mt][j] + b0) + c1 * (aB[nt][mt][j] + b1);
                    v = fmaxf(v, 0.f);
                    *(_Float16*)(smc + H1_B + ((row * 512 + col * 2) ^ SWZ(row))) = (_Float16)v;
                }
            }
        }
    }
    __syncthreads();

    // ---------- E2: H2 = relu(blend(H1 @ ew2[e]^T + eb2[e]))  M=32 N=128x2 K=256 ----------
    {
        f32x4 cA[2], cB[2];
        #pragma unroll
        for (int mt = 0; mt < 2; ++mt) { cA[mt] = {0,0,0,0}; cB[mt] = {0,0,0,0}; }
        const int col = wv * 16 + l15;
        auto ldE2 = [&](int kc, int ex) -> half8 {
            if constexpr (USE_WS) {
                return *(const half8*)(wsw + WS_E2 + ((wv + ex * 8) * 8 + kc) * 512 + lB);
            } else {
                const int g = kc * 4 + kgrp;
                return cvt8(ew2 + (col + ex * 128) * 256 + g * 8);
            }
        };
        half8 b0 = ldE2(0, 0), b1 = ldE2(0, 1);
        #pragma unroll
        for (int kc = 0; kc < 8; ++kc) {
            const half8 c0f = b0, c1f = b1;
            if (kc < 7) { b0 = ldE2(kc + 1, 0); b1 = ldE2(kc + 1, 1); }
            const int koff = kc * 64 + kg16;
            #pragma unroll
            for (int mt = 0; mt < 2; ++mt) {
                const int row = mt * 16 + l15;
                const half8 af = *(const half8*)(smc + H1_B + ((row * 512 + koff) ^ SWZ(row)));
                cA[mt] = MFMA16(af, c0f, cA[mt]);
                cB[mt] = MFMA16(af, c1f, cB[mt]);
            }
        }
        __syncthreads();   // all H1 reads done before H2 overlays H1 low half
        const float b0s = eb2[col], b1s = eb2[128 + col];
        #pragma unroll
        for (int mt = 0; mt < 2; ++mt) {
            #pragma unroll
            for (int j = 0; j < 4; ++j) {
                const int row = mt * 16 + kgrp * 4 + j;
                const half4 cc = *(const half4*)(smc + S_B + ((row * 768 + 752) ^ SWZ(row)));
                const float c0 = (float)cc[0] + (float)cc[1];
                const float c1 = (float)cc[2] + (float)cc[3];
                float v = c0 * (cA[mt][j] + b0s) + c1 * (cB[mt][j] + b1s);
                v = fmaxf(v, 0.f);
                *(_Float16*)(smc + H2_B + ((row * 256 + col * 2) ^ SWZ(row))) = (_Float16)v;
            }
        }
    }
    __syncthreads();

    // ---------- E3: mu = tanh(blend(H2 @ ewm[e]^T + ebm[e]))  M=32 N=17x2 K=128 ----------
    if (wv < 4) {
        const int colt = wv & 1;      // col tile (2x16 covers 17)
        const int mt   = wv >> 1;     // row tile
        f32x4 c0a = {0,0,0,0}, c1a = {0,0,0,0};
        const int col  = colt * 16 + l15;
        const bool vcol = (col < 17);
        const int arow = mt * 16 + l15;
        for (int kc = 0; kc < 4; ++kc) {
            const int koff = kc * 64 + kg16;
            const half8 af = *(const half8*)(smc + H2_B + ((arow * 256 + koff) ^ SWZ(arow)));
            half8 b0, b1;
            if constexpr (USE_WS) {
                b0 = *(const half8*)(wsw + WS_EM + (colt * 4 + kc) * 512 + lB);
                b1 = *(const half8*)(wsw + WS_EM + ((2 + colt) * 4 + kc) * 512 + lB);
            } else {
                const int g = kc * 4 + kgrp;
                b0 = vcol ? cvt8(ewm + col * 128 + g * 8)        : zf;
                b1 = vcol ? cvt8(ewm + (17 + col) * 128 + g * 8) : zf;
            }
            c0a = MFMA16(af, b0, c0a);
            c1a = MFMA16(af, b1, c1a);
        }
        if (vcol) {
            const float b0 = ebm[col], b1 = ebm[17 + col];
            #pragma unroll
            for (int j = 0; j < 4; ++j) {
                const int row = mt * 16 + kgrp * 4 + j;
                const half4 cc = *(const half4*)(smc + S_B + ((row * 768 + 752) ^ SWZ(row)));
                const float c0 = (float)cc[0] + (float)cc[1];
                const float c1 = (float)cc[2] + (float)cc[3];
                const float v = c0 * (c0a[j] + b0) + c1 * (c1a[j] + b1);
                out[(long)(base + row) * 17 + col] = tanhf(v);
            }
        }
    }
}

extern "C" void kernel_launch(void* const* d_in, const int* in_sizes, int n_in,
                              void* d_out, int out_size, void* d_ws, size_t ws_size,
                              hipStream_t stream) {
    (void)in_sizes; (void)n_in; (void)out_size;
    const float* states = (const float*)d_in[0];
    const float* bw1 = (const float*)d_in[1];
    const float* bb1 = (const float*)d_in[2];
    const float* bw2 = (const float*)d_in[3];
    const float* bb2 = (const float*)d_in[4];
    const float* bwo = (const float*)d_in[5];
    const float* bbo = (const float*)d_in[6];
    const float* ew1 = (const float*)d_in[7];
    const float* eb1 = (const float*)d_in[8];
    const float* ew2 = (const float*)d_in[9];
    const float* eb2 = (const float*)d_in[10];
    const float* ewm = (const float*)d_in[11];
    const float* ebm = (const float*)d_in[12];
    float* out = (float*)d_out;

    const int nblk = 65536 / MT;   // 2048

    if (d_ws != nullptr && ws_size >= (size_t)WS_BYTES) {
        _Float16* wsw = (_Float16*)d_ws;
        prep_weights<<<dim3((WS_HALFS + 255) / 256), dim3(256), 0, stream>>>(
            bw1, bw2, ew1, ew2, ewm, wsw);
        actor_kernel<true><<<dim3(nblk), dim3(T), LDS_BYTES, stream>>>(
            states, bw1, bb1, bw2, bb2, bwo, bbo,
            ew1, eb1, ew2, eb2, ewm, ebm, wsw, out);
    } else {
        actor_kernel<false><<<dim3(nblk), dim3(T), LDS_BYTES, stream>>>(
            states, bw1, bb1, bw2, bb2, bwo, bbo,
            ew1, eb1, ew2, eb2, ewm, ebm, nullptr, out);
    }
}